// Round 6
// baseline (1563.236 us; speedup 1.0000x reference)
//
#include <hip/hip_runtime.h>
#include <math.h>

// ---------------------------------------------------------------------------
// RetentionBlock: LN1 -> QKVG proj -> retention scan -> Wo + residual ->
//                 LN2 -> FFN(gelu) + residual
// B=4, L=4096, D_MODEL=1024, H=16, DH=64. All global inputs f32.
// R14: faithful m201 8-phase port. Differences vs failed R9/R11:
//   - FINE staging interleave: 2 global_load_lds per phase (1 half-tile),
//     in region-read-order: B-hi(t+1)@p1, A-lo(t+2)@p2, B-lo(t+2)@p3,
//     A-hi(t+2)@p4 (each dest region read-complete >=2 barriers earlier).
//   - Counted vmcnt(6) ONCE per K-tile at p4 (3 half-tiles in flight);
//     prologue 7 pairs -> vmcnt(6); epilogue vmcnt(0) at t=NT-2.
//   - NO sched_barrier(0) (m141/m196: pins defeat the scheduler).
//   - raw s_barrier everywhere in the loop (no vmcnt-0 __syncthreads).
//   Data path (XOR swizzle both-sides, fragment maps, epilogue) identical
//   to R11 which passed validation (absmax 0.03125, 0 bank conflicts).
// ---------------------------------------------------------------------------

#define D_MODEL 1024
#define LSEQ    4096
#define BATCH   4
#define NROWS   (BATCH * LSEQ)      // 16384
#define HEADS   16
#define DH      64
#define CHUNK   128
#define NCH     (LSEQ / CHUNK)      // 32

typedef short  short8  __attribute__((ext_vector_type(8)));
typedef short  short4v __attribute__((ext_vector_type(4)));
typedef float  float4v __attribute__((ext_vector_type(4)));

__device__ inline short f2bf(float f) {
    unsigned u = __float_as_uint(f);
    u += 0x7fffu + ((u >> 16) & 1u);   // round-to-nearest-even
    return (short)(u >> 16);
}
__device__ inline float bf2f(short s) {
    return __uint_as_float(((unsigned)(unsigned short)s) << 16);
}

// async global->LDS, 16 bytes per lane; dest = wave-uniform base + lane*16
__device__ inline void load_lds16(const short* g, short* l) {
    __builtin_amdgcn_global_load_lds(
        (const __attribute__((address_space(1))) void*)g,
        (__attribute__((address_space(3))) void*)l,
        16, 0, 0);
}

// ---------------------------------------------------------------------------
// Transpose f32 [R][C] -> bf16 [C][R]
// ---------------------------------------------------------------------------
__global__ __launch_bounds__(1024) void transpose_f32_bf16(
    const float* __restrict__ in, short* __restrict__ out, int R, int C)
{
    __shared__ float tile[32][33];
    int tx = threadIdx.x, ty = threadIdx.y;
    int r = blockIdx.y * 32 + ty;
    int c = blockIdx.x * 32 + tx;
    tile[ty][tx] = in[(size_t)r * C + c];
    __syncthreads();
    out[(size_t)(blockIdx.x * 32 + ty) * R + blockIdx.y * 32 + tx] =
        f2bf(tile[tx][ty]);
}

// concat bq|bk|bv|bg -> bias_qkvg[4096]
__global__ __launch_bounds__(256) void concat_bias(
    const float* __restrict__ bq, const float* __restrict__ bk,
    const float* __restrict__ bv, const float* __restrict__ bg,
    float* __restrict__ out)
{
    int i = blockIdx.x * 256 + threadIdx.x;
    const float* src = (i < 1024) ? bq : (i < 2048) ? bk : (i < 3072) ? bv : bg;
    out[i] = src[i & 1023];
}

// ---------------------------------------------------------------------------
// Row LayerNorm: f32 [row][1024] -> bf16 [row][1024]. 1 block / row.
// ---------------------------------------------------------------------------
__global__ __launch_bounds__(256) void ln_kernel(
    const float* __restrict__ x, const float* __restrict__ g,
    const float* __restrict__ b, short* __restrict__ y)
{
    int row = blockIdx.x;
    int tid = threadIdx.x;
    const float4* xr = (const float4*)(x + (size_t)row * D_MODEL);
    float4 v = xr[tid];
    float s  = v.x + v.y + v.z + v.w;
    float ss = v.x * v.x + v.y * v.y + v.z * v.z + v.w * v.w;
    #pragma unroll
    for (int off = 32; off > 0; off >>= 1) {
        s  += __shfl_down(s, off);
        ss += __shfl_down(ss, off);
    }
    __shared__ float sbuf[8];
    int wv = tid >> 6, ln = tid & 63;
    if (ln == 0) { sbuf[wv] = s; sbuf[4 + wv] = ss; }
    __syncthreads();
    float tot  = sbuf[0] + sbuf[1] + sbuf[2] + sbuf[3];
    float tot2 = sbuf[4] + sbuf[5] + sbuf[6] + sbuf[7];
    float mu  = tot * (1.0f / D_MODEL);
    float var = tot2 * (1.0f / D_MODEL) - mu * mu;
    float rs  = rsqrtf(var + 1e-5f);
    float4 gg = ((const float4*)g)[tid];
    float4 bb = ((const float4*)b)[tid];
    short4v o;
    o.x = f2bf((v.x - mu) * rs * gg.x + bb.x);
    o.y = f2bf((v.y - mu) * rs * gg.y + bb.y);
    o.z = f2bf((v.z - mu) * rs * gg.z + bb.z);
    o.w = f2bf((v.w - mu) * rs * gg.w + bb.w);
    ((short4v*)y)[(size_t)row * 256 + tid] = o;
}

// ---------------------------------------------------------------------------
// bf16 MFMA GEMM, 256x256 tile, 8 waves (2Mx4N), BK=64, m201 8-phase.
// C[M][N] = A[M][K](bf16) * BT[N][K](bf16)^T, fused epilogue.
// LDS: As/Bs [2 dbuf][256 rows][64 k] bf16, 128 KiB total, 1 block/CU.
// Element (r,c) at linear r*64 + (c ^ ((r&7)<<3)); staged via linear-dest
// global_load_lds with inverse XOR folded into the SOURCE column; ds_read
// applies the same XOR (both-sides rule; verified: 0 conflicts, absmax ok).
// Per K-tile block (4 phases, each {ds_read | stage 2 loads | bar | prio1 |
// 16 MFMA | prio0 | bar}):
//   p1: read A(qr0)+B(qc0); stage B-hi(t+1) -> other buf
//   p2: read B(qc1);        stage A-lo(t+2) -> same buf
//   p3: read A(qr1);        stage B-lo(t+2)
//   p4: (no reads);         stage A-hi(t+2); s_waitcnt vmcnt(6)
// vmcnt(6) = 3 half-tiles (newest) allowed in flight -> tile t+1 resident.
// mode 0: out_bf16 = (col>=3072 ? sigmoid : id)(acc + bias)        [QKVG]
// mode 1: out_f32  = acc + bias + res   (res==outf in-place is OK) [x2 / final]
// mode 2: out_bf16 = gelu_exact(acc + bias)                        [FFN mid]
// ---------------------------------------------------------------------------
__global__ __launch_bounds__(512, 2) void gemm_bf16(
    const short* __restrict__ A, const short* __restrict__ BT,
    const float* __restrict__ bias, const float* __restrict__ res,
    float* __restrict__ outf, short* __restrict__ outb,
    int M, int N, int K, int mode)
{
    __shared__ short As[2][16384];   // [dbuf][256*64]
    __shared__ short Bs[2][16384];

    // ---- XCD-bijective swizzle (nwg % 8 == 0 for all our launches),
    //      then M-major decode: 64 consecutive wg share one 256-col B strip.
    const int gx  = gridDim.x;                       // 64 (M blocks)
    const int nwg = gx * gridDim.y;
    const int lin = blockIdx.x + blockIdx.y * gx;
    const int cpx = nwg >> 3;
    const int wg  = (lin & 7) * cpx + (lin >> 3);
    const int bx  = wg % gx;
    const int by  = wg / gx;
    const int row0 = bx * 256;
    const int col0 = by * 256;

    const int tid  = threadIdx.x;
    const int wave = tid >> 6;
    const int lane = tid & 63;
    const int wm   = wave >> 2;          // 0..1  (row half of 256)
    const int wn   = wave & 3;           // 0..3  (64-col strip)
    const int lm   = lane & 15;          // row within 16-tile
    const int q    = lane >> 4;          // k-group 0..3
    const int kq0  = ((q ^ (lm & 7)) << 3);          // ks=0 col offset (elems)
    // ks=1 offset = kq0 ^ 32

    // ---- staging: thread covers rows (tid>>3)+{0,64,128,192}, 8 elems each;
    //      source column pre-swizzled so linear LDS dest == swizzled layout.
    const int csw = (((tid & 7) ^ ((tid >> 3) & 7)) << 3);
    const short* gA = A  + (size_t)(row0 + (tid >> 3)) * K + csw;
    const short* gB = BT + (size_t)(col0 + (tid >> 3)) * K + csw;
    short* stA = &As[0][0] + tid * 8;    // + buf*16384 + chunk*4096
    short* stB = &Bs[0][0] + tid * 8;
    const size_t K64 = (size_t)64 * K;

    float4v acc[8][4];
    #pragma unroll
    for (int i = 0; i < 8; i++)
        #pragma unroll
        for (int j = 0; j < 4; j++)
            acc[i][j] = (float4v)(0.0f);

    const int NT = K >> 6;               // 16 or 64 (even, >= 4)

    const int aro = lm * 64;             // + (qr*64 + i*16)*64
    const int bro = ((wn & 1) * 64 + lm) * 64;   // + (qc*32 + j*16)*64

    short8 aF[4][2];        // A frags for current qr
    short8 bF[2][2][2];     // B frags [qc][j][ks], resident whole tile

#define MFMA8(QR, QC)                                                        \
    _Pragma("unroll")                                                        \
    for (int ks = 0; ks < 2; ks++)                                           \
        _Pragma("unroll")                                                    \
        for (int i = 0; i < 4; i++)                                          \
            _Pragma("unroll")                                                \
            for (int j = 0; j < 2; j++)                                      \
                acc[(QR) * 4 + i][(QC) * 2 + j] =                            \
                    __builtin_amdgcn_mfma_f32_16x16x32_bf16(                 \
                        aF[i][ks], bF[QC][j][ks],                            \
                        acc[(QR) * 4 + i][(QC) * 2 + j], 0, 0, 0);

#define DS_A_QR(Ab, QR)                                                      \
    _Pragma("unroll")                                                        \
    for (int i = 0; i < 4; i++) {                                            \
        const int ar = aro + ((QR) * 64 + i * 16) * 64;                      \
        aF[i][0] = *(const short8*)&(Ab)[ar + kq0];                          \
        aF[i][1] = *(const short8*)&(Ab)[ar + (kq0 ^ 32)];                   \
    }

#define DS_B_QC(Bb, QC)                                                      \
    _Pragma("unroll")                                                        \
    for (int j = 0; j < 2; j++) {                                            \
        const int br = bro + ((QC) * 32 + j * 16) * 64;                      \
        bF[QC][j][0] = *(const short8*)&(Bb)[br + kq0];                      \
        bF[QC][j][1] = *(const short8*)&(Bb)[br + (kq0 ^ 32)];               \
    }

#define BAR __builtin_amdgcn_s_barrier()
#define PRIO1 __builtin_amdgcn_s_setprio(1)
#define PRIO0 __builtin_amdgcn_s_setprio(0)

    // ---- prologue: tile0 (4 pairs) + tile1 (A-lo, B-lo, A-hi) ----
    load_lds16(gA,                stA);                // t0 A-lo
    load_lds16(gA + 2 * K64,      stA + 8192);
    load_lds16(gB,                stB);                // t0 B-lo
    load_lds16(gB + 2 * K64,      stB + 8192);
    load_lds16(gA + K64,          stA + 4096);         // t0 A-hi
    load_lds16(gA + 3 * K64,      stA + 12288);
    load_lds16(gB + K64,          stB + 4096);         // t0 B-hi
    load_lds16(gB + 3 * K64,      stB + 12288);
    load_lds16(gA + 64,           stA + 16384);        // t1 A-lo
    load_lds16(gA + 2 * K64 + 64, stA + 16384 + 8192);
    load_lds16(gB + 64,           stB + 16384);        // t1 B-lo
    load_lds16(gB + 2 * K64 + 64, stB + 16384 + 8192);
    load_lds16(gA + K64 + 64,     stA + 16384 + 4096); // t1 A-hi
    load_lds16(gA + 3 * K64 + 64, stA + 16384 + 12288);
    asm volatile("s_waitcnt vmcnt(6)" ::: "memory");   // t0 resident
    BAR;

#define BLOCK(T, CUR)                                                        \
    {                                                                        \
        const short* Ab = &As[0][0] + (CUR) + wm * 8192;                     \
        const short* Bb = &Bs[0][0] + (CUR) + (wn >> 1) * 8192;              \
        const int kb1 = ((T) + 1) << 6;                                      \
        const int kb2 = ((T) + 2) << 6;                                      \
        const bool p1ok = (T) + 1 < NT, p2ok = (T) + 2 < NT;                 \
        /* phase 1: read A(qr0)+B(qc0); stage B-hi(t+1) -> other buf */      \
        DS_A_QR(Ab, 0)                                                       \
        DS_B_QC(Bb, 0)                                                       \
        if (p1ok) {                                                          \
            load_lds16(gB + K64 + kb1,     stB + ((CUR) ^ 16384) + 4096);    \
            load_lds16(gB + 3 * K64 + kb1, stB + ((CUR) ^ 16384) + 12288);   \
        }                                                                    \
        BAR; PRIO1; MFMA8(0, 0) PRIO0; BAR;                                  \
        /* phase 2: read B(qc1); stage A-lo(t+2) -> same buf */              \
        DS_B_QC(Bb, 1)                                                       \
        if (p2ok) {                                                          \
            load_lds16(gA + kb2,           stA + (CUR));                     \
            load_lds16(gA + 2 * K64 + kb2, stA + (CUR) + 8192);              \
        }                                                                    \
        BAR; PRIO1; MFMA8(0, 1) PRIO0; BAR;                                  \
        /* phase 3: read A(qr1); stage B-lo(t+2) */                          \
        DS_A_QR(Ab, 1)                                                       \
        if (p2ok) {                                                          \
            load_lds16(gB + kb2,           stB + (CUR));                     \
            load_lds16(gB + 2 * K64 + kb2, stB + (CUR) + 8192);              \
        }                                                                    \
        BAR; PRIO1; MFMA8(1, 0) PRIO0; BAR;                                  \
        /* phase 4: stage A-hi(t+2); counted wait; MFMA Q11 */               \
        if (p2ok) {                                                          \
            load_lds16(gA + K64 + kb2,     stA + (CUR) + 4096);              \
            load_lds16(gA + 3 * K64 + kb2, stA + (CUR) + 12288);             \
            asm volatile("s_waitcnt vmcnt(6)" ::: "memory");                 \
        } else if (p1ok) {                                                   \
            asm volatile("s_waitcnt vmcnt(0)" ::: "memory");                 \
        }                                                                    \
        BAR; PRIO1; MFMA8(1, 1) PRIO0; BAR;                                  \
    }

    for (int t = 0; t < NT; t += 2) {
        BLOCK(t,     0)
        BLOCK(t + 1, 16384)
    }
#undef BLOCK
#undef MFMA8
#undef DS_A_QR
#undef DS_B_QC
#undef BAR
#undef PRIO1
#undef PRIO0

    // ---- epilogue: C/D layout row=(lane>>4)*4+reg, col=lane&15
    const int r4 = q << 2;
    #pragma unroll
    for (int ai = 0; ai < 8; ai++) {
        const int rowg = row0 + wm * 128 + (ai >> 2) * 64 + (ai & 3) * 16 + r4;
        #pragma unroll
        for (int bj = 0; bj < 4; bj++) {
            const int colg = col0 + wn * 64 + (bj >> 1) * 32 + (bj & 1) * 16 + lm;
            const float bcol = bias[colg];
            #pragma unroll
            for (int r2 = 0; r2 < 4; r2++) {
                size_t idx = (size_t)(rowg + r2) * N + colg;
                float v = acc[ai][bj][r2] + bcol;
                if (mode == 0) {
                    if (colg >= 3072) v = 1.0f / (1.0f + expf(-v));
                    outb[idx] = f2bf(v);
                } else if (mode == 1) {
                    outf[idx] = v + res[idx];
                } else {
                    v = 0.5f * v * (1.0f + erff(v * 0.70710678118654752f));
                    outb[idx] = f2bf(v);
                }
            }
        }
    }
}

// ---------------------------------------------------------------------------
// Retention scan (chunk-parallel). qkvg bf16 [16384][4096]: q|k|v|g sections.
// channel c = b*1024 + h*64 + d  (4096 channels), chunks of 128 timesteps.
// ---------------------------------------------------------------------------
__global__ __launch_bounds__(256) void scan_pass1(
    const short* __restrict__ qkvg, const float* __restrict__ dlogit,
    float* __restrict__ carry)
{
    int j  = blockIdx.x >> 4;
    int c  = ((blockIdx.x & 15) << 8) + threadIdx.x;
    int b  = c >> 10;
    int col = c & 1023;
    float decay = 1.0f / (1.0f + expf(-dlogit[col >> 6]));
    size_t base = ((size_t)b * LSEQ + j * CHUNK) * 4096 + col;
    float s = 0.0f;
    for (int t = 0; t < CHUNK; ++t) {
        float kk = bf2f(qkvg[base + 1024]);
        float vv = bf2f(qkvg[base + 2048]);
        s = decay * s + kk * vv;
        base += 4096;
    }
    carry[j * 4096 + c] = s;
}

__global__ __launch_bounds__(256) void scan_combine(
    const float* __restrict__ carry, const float* __restrict__ dlogit,
    float* __restrict__ sinit)
{
    int c = blockIdx.x * 256 + threadIdx.x;
    float decay = 1.0f / (1.0f + expf(-dlogit[(c & 1023) >> 6]));
    float dp = powf(decay, (float)CHUNK);
    float s = 0.0f;
    for (int j = 0; j < NCH; ++j) {
        sinit[j * 4096 + c] = s;
        s = dp * s + carry[j * 4096 + c];
    }
}

__global__ __launch_bounds__(256) void scan_pass2(
    const short* __restrict__ qkvg, const float* __restrict__ dlogit,
    const float* __restrict__ sinit, short* __restrict__ att)
{
    int j  = blockIdx.x >> 4;
    int c  = ((blockIdx.x & 15) << 8) + threadIdx.x;
    int b  = c >> 10;
    int col = c & 1023;
    float decay = 1.0f / (1.0f + expf(-dlogit[col >> 6]));
    float s = sinit[j * 4096 + c];
    size_t base  = ((size_t)b * LSEQ + j * CHUNK) * 4096 + col;
    size_t obase = ((size_t)b * LSEQ + j * CHUNK) * 1024 + col;
    for (int t = 0; t < CHUNK; ++t) {
        float qq = bf2f(qkvg[base]);
        float kk = bf2f(qkvg[base + 1024]);
        float vv = bf2f(qkvg[base + 2048]);
        float gg = bf2f(qkvg[base + 3072]);
        s = decay * s + kk * vv;
        att[obase] = f2bf(gg * qq * s * 0.125f);   // scale = DH^-0.5
        base += 4096; obase += 1024;
    }
}

// ---------------------------------------------------------------------------
extern "C" void kernel_launch(void* const* d_in, const int* in_sizes, int n_in,
                              void* d_out, int out_size, void* d_ws, size_t ws_size,
                              hipStream_t stream)
{
    const float* x      = (const float*)d_in[0];
    const float* ln1_g  = (const float*)d_in[1];
    const float* ln1_b  = (const float*)d_in[2];
    const float* Wq     = (const float*)d_in[3];
    const float* bq     = (const float*)d_in[4];
    const float* Wk     = (const float*)d_in[5];
    const float* bk     = (const float*)d_in[6];
    const float* Wv     = (const float*)d_in[7];
    const float* bv     = (const float*)d_in[8];
    const float* Wg     = (const float*)d_in[9];
    const float* bg     = (const float*)d_in[10];
    const float* dlog   = (const float*)d_in[11];
    const float* Wo     = (const float*)d_in[12];
    const float* bo     = (const float*)d_in[13];
    const float* ln2_g  = (const float*)d_in[14];
    const float* ln2_b  = (const float*)d_in[15];
    const float* W1     = (const float*)d_in[16];
    const float* b1     = (const float*)d_in[17];
    const float* W2     = (const float*)d_in[18];
    const float* b2     = (const float*)d_in[19];
    float* out = (float*)d_out;

    char* ws = (char*)d_ws;
    size_t off = 0;
    auto alloc = [&](size_t bytes) -> void* {
        void* p = ws + off;
        off += (bytes + 255) & ~(size_t)255;
        return p;
    };
    // ---- workspace layout (~196 MB total) ----
    short* WqkvgT = (short*)alloc((size_t)4096 * 1024 * 2);   // 8 MB  [n=4096][k=1024]
    short* WoT    = (short*)alloc((size_t)1024 * 1024 * 2);   // 2 MB  [n=1024][k=1024]
    short* W1T    = (short*)alloc((size_t)4096 * 1024 * 2);   // 8 MB  [n=4096][k=1024]
    short* W2T    = (short*)alloc((size_t)1024 * 4096 * 2);   // 8 MB  [n=1024][k=4096]
    float* biasq  = (float*)alloc((size_t)4096 * 4);
    float* carry  = (float*)alloc((size_t)NCH * 4096 * 4);    // 0.5 MB
    float* sinit  = (float*)alloc((size_t)NCH * 4096 * 4);    // 0.5 MB
    short* bufA   = (short*)alloc((size_t)NROWS * 1024 * 2);  // 32 MB: y -> att -> h
    short* bufB   = (short*)alloc((size_t)NROWS * 4096 * 2);  // 128 MB: qkvg -> ff1
    // x2 lives in d_out (64 MB saved); final GEMM does in-place residual.
    float* x2 = out;
    short* ybuf = bufA;   // LN1 output
    short* att  = bufA;   // scan output (ybuf dead by then)
    short* hbuf = bufA;   // LN2 output (att dead by then)
    short* qkvg = bufB;
    short* ff1  = bufB;   // qkvg dead after scan_pass2
    (void)in_sizes; (void)n_in; (void)out_size;

    if (off > ws_size) return;  // ws too small: fail validation cleanly, not a segfault

    dim3 tb(32, 32);
    // weight prep: transpose + bf16 cast (must rerun every call; ws is poisoned)
    transpose_f32_bf16<<<dim3(32, 32), tb, 0, stream>>>(Wq, WqkvgT + 0 * 1024 * 1024, 1024, 1024);
    transpose_f32_bf16<<<dim3(32, 32), tb, 0, stream>>>(Wk, WqkvgT + 1 * 1024 * 1024, 1024, 1024);
    transpose_f32_bf16<<<dim3(32, 32), tb, 0, stream>>>(Wv, WqkvgT + 2 * 1024 * 1024, 1024, 1024);
    transpose_f32_bf16<<<dim3(32, 32), tb, 0, stream>>>(Wg, WqkvgT + 3 * 1024 * 1024, 1024, 1024);
    transpose_f32_bf16<<<dim3(32, 32), tb, 0, stream>>>(Wo, WoT, 1024, 1024);
    transpose_f32_bf16<<<dim3(128, 32), tb, 0, stream>>>(W1, W1T, 1024, 4096);
    transpose_f32_bf16<<<dim3(32, 128), tb, 0, stream>>>(W2, W2T, 4096, 1024);
    concat_bias<<<16, 256, 0, stream>>>(bq, bk, bv, bg, biasq);

    // LN1: x -> y(bf16)
    ln_kernel<<<NROWS, 256, 0, stream>>>(x, ln1_g, ln1_b, ybuf);

    // QKVG projection (fused bias + sigmoid on G): grid 64x16 = 1024 wg
    gemm_bf16<<<dim3(64, 16), 512, 0, stream>>>(
        ybuf, WqkvgT, biasq, nullptr, nullptr, qkvg, NROWS, 4096, 1024, 0);

    // retention scan
    scan_pass1 <<<NCH * 16, 256, 0, stream>>>(qkvg, dlog, carry);
    scan_combine<<<16, 256, 0, stream>>>(carry, dlog, sinit);
    scan_pass2 <<<NCH * 16, 256, 0, stream>>>(qkvg, dlog, sinit, att);

    // output projection + residual: x2 = x + att@Wo + bo   (x2 == d_out)
    gemm_bf16<<<dim3(64, 4), 512, 0, stream>>>(
        att, WoT, bo, x, x2, nullptr, NROWS, 1024, 1024, 1);

    // LN2: x2 -> h(bf16)
    ln_kernel<<<NROWS, 256, 0, stream>>>(x2, ln2_g, ln2_b, hbuf);

    // FFN: ff1 = gelu(h@W1 + b1)  (bf16)
    gemm_bf16<<<dim3(64, 16), 512, 0, stream>>>(
        hbuf, W1T, b1, nullptr, nullptr, ff1, NROWS, 4096, 1024, 2);

    // out = x2 + ff1@W2 + b2   (in-place residual on d_out)
    gemm_bf16<<<dim3(64, 4), 512, 0, stream>>>(
        ff1, W2T, b2, x2, out, nullptr, NROWS, 1024, 4096, 1);
}

// Round 7
// 892.763 us; speedup vs baseline: 1.7510x; 1.7510x over previous
//
#include <hip/hip_runtime.h>
#include <math.h>

// ---------------------------------------------------------------------------
// RetentionBlock: LN1 -> QKVG proj -> retention scan -> Wo + residual ->
//                 LN2 -> FFN(gelu) + residual
// B=4, L=4096, D_MODEL=1024, H=16, DH=64. All global inputs f32.
// R15: the 256^2 8-phase branch is dead (3 ports: 267/300/579us vs R8 226us).
//     Revert gemm to the EXACT round-0 R8 kernel (919us total, VGPR 56,
//     0 bank conflicts, 4 blocks/CU). Harvest safe non-gemm wins:
//     (1) ALL weight prep (7 transposes + bias concat) fused into ONE
//         flat-grid kernel -> saves ~6 serial launch gaps;
//     (2) LayerNorm rewritten wave-per-row: 4 rows/block, grid 16384->4096,
//         no __syncthreads, pure shfl_xor reduce, 64B/lane loads.
// ---------------------------------------------------------------------------

#define D_MODEL 1024
#define LSEQ    4096
#define BATCH   4
#define NROWS   (BATCH * LSEQ)      // 16384
#define HEADS   16
#define DH      64
#define CHUNK   128
#define NCH     (LSEQ / CHUNK)      // 32

typedef short  short8  __attribute__((ext_vector_type(8)));
typedef short  short4v __attribute__((ext_vector_type(4)));
typedef float  float4v __attribute__((ext_vector_type(4)));

__device__ inline short f2bf(float f) {
    unsigned u = __float_as_uint(f);
    u += 0x7fffu + ((u >> 16) & 1u);   // round-to-nearest-even
    return (short)(u >> 16);
}
__device__ inline float bf2f(short s) {
    return __uint_as_float(((unsigned)(unsigned short)s) << 16);
}

// async global->LDS, 16 bytes per lane; dest = wave-uniform base + lane*16
__device__ inline void load_lds16(const short* g, short* l) {
    __builtin_amdgcn_global_load_lds(
        (const __attribute__((address_space(1))) void*)g,
        (__attribute__((address_space(3))) void*)l,
        16, 0, 0);
}

// ---------------------------------------------------------------------------
// Fused weight prep: ONE launch does all 7 transposes (f32 [R][C] -> bf16
// [C][R]) + the 4-way bias concat. Flat grid, each block decodes its job:
//   blocks [0,5120):     5 square 1024x1024 transposes (Wq,Wk,Wv,Wg -> WqkvgT
//                        sections; Wo -> WoT), 1024 tiles each
//   blocks [5120,9216):  W1 1024x4096 -> W1T, tiles bx in [0,128), by in [0,32)
//   blocks [9216,13312): W2 4096x1024 -> W2T, tiles bx in [0,32), by in [0,128)
//   blocks [13312,13316): bias concat bq|bk|bv|bg -> biasq[4096]
// ---------------------------------------------------------------------------
__global__ __launch_bounds__(1024) void prep_weights(
    const float* __restrict__ Wq, const float* __restrict__ Wk,
    const float* __restrict__ Wv, const float* __restrict__ Wg,
    const float* __restrict__ Wo, const float* __restrict__ W1,
    const float* __restrict__ W2,
    const float* __restrict__ bq, const float* __restrict__ bk,
    const float* __restrict__ bv, const float* __restrict__ bg,
    short* __restrict__ WqkvgT, short* __restrict__ WoT,
    short* __restrict__ W1T, short* __restrict__ W2T,
    float* __restrict__ biasq)
{
    const int bid = blockIdx.x;
    const int tx = threadIdx.x, ty = threadIdx.y;

    if (bid >= 13312) {                  // bias concat
        int i = (bid - 13312) * 1024 + ty * 32 + tx;
        const float* src = (i < 1024) ? bq : (i < 2048) ? bk
                         : (i < 3072) ? bv : bg;
        biasq[i] = src[i & 1023];
        return;
    }

    const float* src; short* dst; int R, C, bx, by;
    if (bid < 5120) {                    // square 1024x1024
        const int m = bid >> 10, t = bid & 1023;
        bx = t & 31; by = t >> 5; R = 1024; C = 1024;
        if (m < 4) { src = (m == 0) ? Wq : (m == 1) ? Wk : (m == 2) ? Wv : Wg;
                     dst = WqkvgT + (size_t)m * 1024 * 1024; }
        else       { src = Wo; dst = WoT; }
    } else if (bid < 9216) {             // W1: R=1024, C=4096
        const int t = bid - 5120;
        bx = t & 127; by = t >> 7; R = 1024; C = 4096;
        src = W1; dst = W1T;
    } else {                             // W2: R=4096, C=1024
        const int t = bid - 9216;
        bx = t & 31; by = t >> 5; R = 4096; C = 1024;
        src = W2; dst = W2T;
    }

    __shared__ float tile[32][33];
    const int r = by * 32 + ty;
    const int c = bx * 32 + tx;
    tile[ty][tx] = src[(size_t)r * C + c];
    __syncthreads();
    dst[(size_t)(bx * 32 + ty) * R + by * 32 + tx] = f2bf(tile[tx][ty]);
}

// ---------------------------------------------------------------------------
// Row LayerNorm, wave-per-row: f32 [row][1024] -> bf16 [row][1024].
// 256 thr = 4 waves = 4 rows/block; no __syncthreads; shfl_xor reduce.
// ---------------------------------------------------------------------------
__global__ __launch_bounds__(256) void ln_kernel(
    const float* __restrict__ x, const float* __restrict__ g,
    const float* __restrict__ b, short* __restrict__ y)
{
    const int wave = threadIdx.x >> 6, lane = threadIdx.x & 63;
    const int row  = blockIdx.x * 4 + wave;
    const float4* xr = (const float4*)(x + (size_t)row * D_MODEL);
    float4 v[4];
    float s = 0.0f, ss = 0.0f;
    #pragma unroll
    for (int qq = 0; qq < 4; qq++) {
        v[qq] = xr[lane + qq * 64];
        s  += v[qq].x + v[qq].y + v[qq].z + v[qq].w;
        ss += v[qq].x * v[qq].x + v[qq].y * v[qq].y
            + v[qq].z * v[qq].z + v[qq].w * v[qq].w;
    }
    #pragma unroll
    for (int off = 32; off > 0; off >>= 1) {
        s  += __shfl_xor(s, off);
        ss += __shfl_xor(ss, off);
    }
    const float mu  = s * (1.0f / D_MODEL);
    const float var = ss * (1.0f / D_MODEL) - mu * mu;
    const float rs  = rsqrtf(var + 1e-5f);
    short4v* yr = (short4v*)(y + (size_t)row * D_MODEL);
    #pragma unroll
    for (int qq = 0; qq < 4; qq++) {
        const float4 gg = ((const float4*)g)[lane + qq * 64];
        const float4 bb = ((const float4*)b)[lane + qq * 64];
        short4v o;
        o.x = f2bf((v[qq].x - mu) * rs * gg.x + bb.x);
        o.y = f2bf((v[qq].y - mu) * rs * gg.y + bb.y);
        o.z = f2bf((v[qq].z - mu) * rs * gg.z + bb.z);
        o.w = f2bf((v[qq].w - mu) * rs * gg.w + bb.w);
        yr[lane + qq * 64] = o;
    }
}

// ---------------------------------------------------------------------------
// bf16 MFMA GEMM: C[M][N] = A[M][K](bf16) * BT[N][K](bf16)^T, fused epilogue.
// Block 256 = 4 waves; tile 128x128; wave owns 64x64 as 4x4 of 16x16x32 MFMA.
// Staging: global_load_lds width=16, double-buffered LDS, 1 barrier/iter.
// LDS slot map (16B units): slot(row, q) = row*4 + (q ^ ((row>>1)&3)).
// Grid swizzle: windows of 8 x-blocks, y fastest (R4 measured-best).
// __launch_bounds__(256,4): cap unified regs at 128/wave -> 4 blocks/CU.
// mode 0: out_bf16 = (col>=3072 ? sigmoid : id)(acc + bias)        [QKVG]
// mode 1: out_f32  = acc + bias + res   (res==outf in-place is OK) [x2 / final]
// mode 2: out_bf16 = gelu_exact(acc + bias)                        [FFN mid]
// (EXACT copy of the measured-best round-0 kernel: 226us/big-gemm, VGPR 56.)
// ---------------------------------------------------------------------------
__global__ __launch_bounds__(256, 4) void gemm_bf16(
    const short* __restrict__ A, const short* __restrict__ BT,
    const float* __restrict__ bias, const float* __restrict__ res,
    float* __restrict__ outf, short* __restrict__ outb,
    int M, int N, int K, int mode)
{
    __shared__ short As[2 * 4096];   // 2 x 8 KB, slot-swizzled
    __shared__ short Bs[2 * 4096];

    // ---- grid swizzle: window = 8 x-values * all y, y fastest inside ----
    const int gx = gridDim.x, gy = gridDim.y;
    const int lin = blockIdx.x + blockIdx.y * gx;
    const int win = 8 * gy;
    const int grp = lin / win;
    const int rem = lin - grp * win;
    const int bx = grp * 8 + (rem & 7);
    const int by = rem >> 3;

    const int tid  = threadIdx.x;
    const int row0 = bx * 128;
    const int col0 = by * 128;
    const int lane = tid & 63;
    const int wave = tid >> 6;
    const int wm = (wave & 1) << 6;
    const int wn = (wave >> 1) << 6;
    const int lm = lane & 15;            // m / n index within 16-tile
    const int q  = lane >> 4;            // kgroup 0..3 of this lane's fragment

    float4v acc[4][4];
    #pragma unroll
    for (int i = 0; i < 4; i++)
        #pragma unroll
        for (int j = 0; j < 4; j++)
            acc[i][j] = (float4v)(0.0f);

    // ---- staging decode (constant per lane; only k0 varies) ----
    const int s0 = wave * 64 + lane;
    const int s1 = 256 + wave * 64 + lane;
    const int r0 = s0 >> 2, q0 = (s0 & 3) ^ ((r0 >> 1) & 3);
    const int r1 = s1 >> 2, q1 = (s1 & 3) ^ ((r1 >> 1) & 3);
    const short* gA0 = A  + (size_t)(row0 + r0) * K + q0 * 8;
    const short* gA1 = A  + (size_t)(row0 + r1) * K + q1 * 8;
    const short* gB0 = BT + (size_t)(col0 + r0) * K + q0 * 8;
    const short* gB1 = BT + (size_t)(col0 + r1) * K + q1 * 8;
    short* lA0 = As + s0 * 8;
    short* lA1 = As + s1 * 8;
    short* lB0 = Bs + s0 * 8;
    short* lB1 = Bs + s1 * 8;

    // fragment-read swizzle: row = 16*t + lm  ->  (row>>1)&3 == (lm>>1)&3
    const int swz = (lm >> 1) & 3;
    const int qs  = q ^ swz;             // swizzled kgroup slot for reads

    // prologue: tile 0 -> buffer 0
    load_lds16(gA0, lA0);
    load_lds16(gA1, lA1);
    load_lds16(gB0, lB0);
    load_lds16(gB1, lB1);

    int p = 0;
    for (int k0 = 0; k0 < K; k0 += 32) {
        __syncthreads();                 // drains this tile's loads + prior reads
        const int kn = k0 + 32;
        const int po = p ^ 1;
        if (kn < K) {                    // prefetch next tile into other buffer
            load_lds16(gA0 + kn, lA0 + po * 4096);
            load_lds16(gA1 + kn, lA1 + po * 4096);
            load_lds16(gB0 + kn, lB0 + po * 4096);
            load_lds16(gB1 + kn, lB1 + po * 4096);
        }
        const short* Ab = As + p * 4096;
        const short* Bb = Bs + p * 4096;

        short8 af[4], bfr[4];
        #pragma unroll
        for (int i = 0; i < 4; i++)
            af[i] = *(const short8*)&Ab[((wm + i * 16 + lm) * 4 + qs) * 8];
        #pragma unroll
        for (int j = 0; j < 4; j++)
            bfr[j] = *(const short8*)&Bb[((wn + j * 16 + lm) * 4 + qs) * 8];
        #pragma unroll
        for (int i = 0; i < 4; i++)
            #pragma unroll
            for (int j = 0; j < 4; j++)
                acc[i][j] = __builtin_amdgcn_mfma_f32_16x16x32_bf16(
                    af[i], bfr[j], acc[i][j], 0, 0, 0);
        p ^= 1;
    }

    const int r4 = (lane >> 4) << 2;     // C/D: row=(lane>>4)*4+reg, col=lane&15
    #pragma unroll
    for (int i = 0; i < 4; i++) {
        #pragma unroll
        for (int j = 0; j < 4; j++) {
            int colg = col0 + wn + j * 16 + lm;
            float bcol = bias[colg];
            #pragma unroll
            for (int r2 = 0; r2 < 4; r2++) {
                int rowg = row0 + wm + i * 16 + r4 + r2;
                size_t idx = (size_t)rowg * N + colg;
                float v = acc[i][j][r2] + bcol;
                if (mode == 0) {
                    if (colg >= 3072) v = 1.0f / (1.0f + expf(-v));
                    outb[idx] = f2bf(v);
                } else if (mode == 1) {
                    outf[idx] = v + res[idx];
                } else {
                    v = 0.5f * v * (1.0f + erff(v * 0.70710678118654752f));
                    outb[idx] = f2bf(v);
                }
            }
        }
    }
}

// ---------------------------------------------------------------------------
// Retention scan (chunk-parallel). qkvg bf16 [16384][4096]: q|k|v|g sections.
// channel c = b*1024 + h*64 + d  (4096 channels), chunks of 128 timesteps.
// ---------------------------------------------------------------------------
__global__ __launch_bounds__(256) void scan_pass1(
    const short* __restrict__ qkvg, const float* __restrict__ dlogit,
    float* __restrict__ carry)
{
    int j  = blockIdx.x >> 4;
    int c  = ((blockIdx.x & 15) << 8) + threadIdx.x;
    int b  = c >> 10;
    int col = c & 1023;
    float decay = 1.0f / (1.0f + expf(-dlogit[col >> 6]));
    size_t base = ((size_t)b * LSEQ + j * CHUNK) * 4096 + col;
    float s = 0.0f;
    for (int t = 0; t < CHUNK; ++t) {
        float kk = bf2f(qkvg[base + 1024]);
        float vv = bf2f(qkvg[base + 2048]);
        s = decay * s + kk * vv;
        base += 4096;
    }
    carry[j * 4096 + c] = s;
}

__global__ __launch_bounds__(256) void scan_combine(
    const float* __restrict__ carry, const float* __restrict__ dlogit,
    float* __restrict__ sinit)
{
    int c = blockIdx.x * 256 + threadIdx.x;
    float decay = 1.0f / (1.0f + expf(-dlogit[(c & 1023) >> 6]));
    float dp = powf(decay, (float)CHUNK);
    float s = 0.0f;
    for (int j = 0; j < NCH; ++j) {
        sinit[j * 4096 + c] = s;
        s = dp * s + carry[j * 4096 + c];
    }
}

__global__ __launch_bounds__(256) void scan_pass2(
    const short* __restrict__ qkvg, const float* __restrict__ dlogit,
    const float* __restrict__ sinit, short* __restrict__ att)
{
    int j  = blockIdx.x >> 4;
    int c  = ((blockIdx.x & 15) << 8) + threadIdx.x;
    int b  = c >> 10;
    int col = c & 1023;
    float decay = 1.0f / (1.0f + expf(-dlogit[col >> 6]));
    float s = sinit[j * 4096 + c];
    size_t base  = ((size_t)b * LSEQ + j * CHUNK) * 4096 + col;
    size_t obase = ((size_t)b * LSEQ + j * CHUNK) * 1024 + col;
    for (int t = 0; t < CHUNK; ++t) {
        float qq = bf2f(qkvg[base]);
        float kk = bf2f(qkvg[base + 1024]);
        float vv = bf2f(qkvg[base + 2048]);
        float gg = bf2f(qkvg[base + 3072]);
        s = decay * s + kk * vv;
        att[obase] = f2bf(gg * qq * s * 0.125f);   // scale = DH^-0.5
        base += 4096; obase += 1024;
    }
}

// ---------------------------------------------------------------------------
extern "C" void kernel_launch(void* const* d_in, const int* in_sizes, int n_in,
                              void* d_out, int out_size, void* d_ws, size_t ws_size,
                              hipStream_t stream)
{
    const float* x      = (const float*)d_in[0];
    const float* ln1_g  = (const float*)d_in[1];
    const float* ln1_b  = (const float*)d_in[2];
    const float* Wq     = (const float*)d_in[3];
    const float* bq     = (const float*)d_in[4];
    const float* Wk     = (const float*)d_in[5];
    const float* bk     = (const float*)d_in[6];
    const float* Wv     = (const float*)d_in[7];
    const float* bv     = (const float*)d_in[8];
    const float* Wg     = (const float*)d_in[9];
    const float* bg     = (const float*)d_in[10];
    const float* dlog   = (const float*)d_in[11];
    const float* Wo     = (const float*)d_in[12];
    const float* bo     = (const float*)d_in[13];
    const float* ln2_g  = (const float*)d_in[14];
    const float* ln2_b  = (const float*)d_in[15];
    const float* W1     = (const float*)d_in[16];
    const float* b1     = (const float*)d_in[17];
    const float* W2     = (const float*)d_in[18];
    const float* b2     = (const float*)d_in[19];
    float* out = (float*)d_out;

    char* ws = (char*)d_ws;
    size_t off = 0;
    auto alloc = [&](size_t bytes) -> void* {
        void* p = ws + off;
        off += (bytes + 255) & ~(size_t)255;
        return p;
    };
    // ---- workspace layout (~196 MB total) ----
    short* WqkvgT = (short*)alloc((size_t)4096 * 1024 * 2);   // 8 MB  [n=4096][k=1024]
    short* WoT    = (short*)alloc((size_t)1024 * 1024 * 2);   // 2 MB  [n=1024][k=1024]
    short* W1T    = (short*)alloc((size_t)4096 * 1024 * 2);   // 8 MB  [n=4096][k=1024]
    short* W2T    = (short*)alloc((size_t)1024 * 4096 * 2);   // 8 MB  [n=1024][k=4096]
    float* biasq  = (float*)alloc((size_t)4096 * 4);
    float* carry  = (float*)alloc((size_t)NCH * 4096 * 4);    // 0.5 MB
    float* sinit  = (float*)alloc((size_t)NCH * 4096 * 4);    // 0.5 MB
    short* bufA   = (short*)alloc((size_t)NROWS * 1024 * 2);  // 32 MB: y -> att -> h
    short* bufB   = (short*)alloc((size_t)NROWS * 4096 * 2);  // 128 MB: qkvg -> ff1
    // x2 lives in d_out (64 MB saved); final GEMM does in-place residual.
    float* x2 = out;
    short* ybuf = bufA;   // LN1 output
    short* att  = bufA;   // scan output (ybuf dead by then)
    short* hbuf = bufA;   // LN2 output (att dead by then)
    short* qkvg = bufB;
    short* ff1  = bufB;   // qkvg dead after scan_pass2
    (void)in_sizes; (void)n_in; (void)out_size;

    if (off > ws_size) return;  // ws too small: fail validation cleanly, not a segfault

    // weight prep: ONE fused launch (7 transposes + bias concat)
    prep_weights<<<13316, dim3(32, 32), 0, stream>>>(
        Wq, Wk, Wv, Wg, Wo, W1, W2, bq, bk, bv, bg,
        WqkvgT, WoT, W1T, W2T, biasq);

    // LN1: x -> y(bf16)   (wave-per-row, 4 rows/block)
    ln_kernel<<<NROWS / 4, 256, 0, stream>>>(x, ln1_g, ln1_b, ybuf);

    // QKVG projection (fused bias + sigmoid on G)
    gemm_bf16<<<dim3(128, 32), 256, 0, stream>>>(
        ybuf, WqkvgT, biasq, nullptr, nullptr, qkvg, NROWS, 4096, 1024, 0);

    // retention scan
    scan_pass1 <<<NCH * 16, 256, 0, stream>>>(qkvg, dlog, carry);
    scan_combine<<<16, 256, 0, stream>>>(carry, dlog, sinit);
    scan_pass2 <<<NCH * 16, 256, 0, stream>>>(qkvg, dlog, sinit, att);

    // output projection + residual: x2 = x + att@Wo + bo   (x2 == d_out)
    gemm_bf16<<<dim3(128, 8), 256, 0, stream>>>(
        att, WoT, bo, x, x2, nullptr, NROWS, 1024, 1024, 1);

    // LN2: x2 -> h(bf16)
    ln_kernel<<<NROWS / 4, 256, 0, stream>>>(x2, ln2_g, ln2_b, hbuf);

    // FFN: ff1 = gelu(h@W1 + b1)  (bf16)
    gemm_bf16<<<dim3(128, 32), 256, 0, stream>>>(
        hbuf, W1T, b1, nullptr, nullptr, ff1, NROWS, 4096, 1024, 2);

    // out = x2 + ff1@W2 + b2   (in-place residual on d_out)
    gemm_bf16<<<dim3(128, 8), 256, 0, stream>>>(
        ff1, W2T, b2, x2, out, nullptr, NROWS, 1024, 4096, 1);
}